// Round 13
// baseline (150.199 us; speedup 1.0000x reference)
//
#include <hip/hip_runtime.h>
#include <hip/hip_bf16.h>
#include <stdint.h>

#define NB 16
#define NS 1024
#define ND 512
#define NO 512
#define NROW (NB*NS)   // 16384
#define SIM_BAND 1.5e-3f

typedef float f32x4 __attribute__((ext_vector_type(4)));
typedef _Float16 f16x8 __attribute__((ext_vector_type(8)));

#define GLOAD_LDS16(g, l) __builtin_amdgcn_global_load_lds( \
    (const __attribute__((address_space(1))) void*)(g), \
    (__attribute__((address_space(3))) void*)(l), 16, 0, 0)

// ---------------- K1: merged W-prep: blocks 0..31 = Wf frag tiles (f16), 32..33 = watt ----------------
__global__ __launch_bounds__(256) void k_prep_w2(const float* __restrict__ W,
                                                 const float* __restrict__ att_src,
                                                 const float* __restrict__ att_dst,
                                                 _Float16* __restrict__ Wf,
                                                 float* __restrict__ watt_s,
                                                 float* __restrict__ watt_d) {
  __shared__ float as_[512], ad_[512];
  int blk = blockIdx.x, tid = threadIdx.x;
  if (blk < 32) {
    int mt = blk>>3, k0c = blk&7;
    size_t base = ((size_t)(mt*8 + k0c))*8192;
    #pragma unroll
    for (int pp = 0; pp < 4; ++pp) {
      int id = pp*256 + tid;
      int kb = id>>9, m = (id>>6)&7, g = (id>>4)&3, r = id&15;
      int o = mt*128 + m*16 + r;
      int d0 = k0c*64 + kb*32 + g*8;
      union { _Float16 h[8]; uint4 u; } pk;
      #pragma unroll
      for (int j = 0; j < 8; ++j) pk.h[j] = (_Float16)W[(size_t)(d0+j)*NO + o];
      *(uint4*)&Wf[base + id*8] = pk.u;
    }
  } else {
    as_[tid] = att_src[tid]; as_[tid+256] = att_src[tid+256];
    ad_[tid] = att_dst[tid]; ad_[tid+256] = att_dst[tid+256];
    __syncthreads();
    int d = (blk-32)*256 + tid;
    const float* wr = W + (size_t)d*NO;
    float s = 0.f, dd = 0.f;
    for (int o = 0; o < NO; o += 4) {
      float4 w = *(const float4*)&wr[o];
      s  = fmaf(w.x, as_[o], fmaf(w.y, as_[o+1], fmaf(w.z, as_[o+2], fmaf(w.w, as_[o+3], s))));
      dd = fmaf(w.x, ad_[o], fmaf(w.y, ad_[o+1], fmaf(w.z, ad_[o+2], fmaf(w.w, ad_[o+3], dd))));
    }
    watt_s[d] = s;
    watt_d[d] = dd;
  }
}

// ---------------- K2: rnorm + a_src/a_dst (via watt) + yf = f16(x*rn) fragment-order ----------------
__global__ __launch_bounds__(256) void k_prep_y(const float* __restrict__ x,
                                                _Float16* __restrict__ yf,
                                                float* __restrict__ rnorm,
                                                float* __restrict__ a_src,
                                                float* __restrict__ a_dst,
                                                const float* __restrict__ watt_s,
                                                const float* __restrict__ watt_d) {
  __shared__ float ws_[512], wd_[512];
  int tid = threadIdx.x, blk = blockIdx.x;
  ws_[tid] = watt_s[tid]; ws_[tid+256] = watt_s[tid+256];
  wd_[tid] = watt_d[tid]; wd_[tid+256] = watt_d[tid+256];
  __syncthreads();
  int r = tid>>2, q = tid&3;
  int grow = blk*64 + r;
  const float* xr = x + (size_t)grow*ND + q*128;
  float ssq = 0.f, as = 0.f, ad = 0.f;
  #pragma unroll
  for (int c8 = 0; c8 < 16; ++c8) {
    float4 v0 = *(const float4*)&xr[c8*8];
    float4 v1 = *(const float4*)&xr[c8*8+4];
    float vv[8] = {v0.x,v0.y,v0.z,v0.w,v1.x,v1.y,v1.z,v1.w};
    #pragma unroll
    for (int j = 0; j < 8; ++j) {
      int c = q*128 + c8*8 + j;
      ssq = fmaf(vv[j], vv[j], ssq);
      as  = fmaf(vv[j], ws_[c], as);
      ad  = fmaf(vv[j], wd_[c], ad);
    }
  }
  ssq += __shfl_xor(ssq, 1, 64); ssq += __shfl_xor(ssq, 2, 64);
  as  += __shfl_xor(as, 1, 64);  as  += __shfl_xor(as, 2, 64);
  ad  += __shfl_xor(ad, 1, 64);  ad  += __shfl_xor(ad, 2, 64);
  float rn = 1.0f / fmaxf(sqrtf(ssq), 1e-12f);
  if (q == 0) { rnorm[grow] = rn; a_src[grow] = as; a_dst[grow] = ad; }
  int trow = grow & (NS-1), b = grow >> 10;
  int m = (trow>>4)&7, rr = trow&15;
  size_t tilebase = ((size_t)(b*8 + (trow>>7)))*65536;
  #pragma unroll
  for (int c8 = 0; c8 < 16; ++c8) {
    int col = q*128 + c8*8;
    int k0c = col>>6, cc = col&63, kb = cc>>5, g = (cc>>3)&3;
    int id = kb*512 + m*64 + g*16 + rr;
    size_t off = tilebase + (size_t)k0c*8192 + id*8;
    float4 v0 = *(const float4*)&xr[c8*8];
    float4 v1 = *(const float4*)&xr[c8*8+4];
    float vv[8] = {v0.x,v0.y,v0.z,v0.w,v1.x,v1.y,v1.z,v1.w};
    union { _Float16 h[8]; uint4 u; } pk;
    #pragma unroll
    for (int j = 0; j < 8; ++j) pk.h[j] = (_Float16)(vv[j]*rn);   // RTN f16, rel err <= 2^-12
    *(uint4*)&yf[off] = pk.u;
  }
}

// ---------------- K3: sim = yf . yf' (f16 MFMA hi-only) -> byte mask (0/1, 2=borderline) ----------------
__global__ __launch_bounds__(256) void k_sim_mfma(const _Float16* __restrict__ yf,
                                                  uint8_t* __restrict__ Mmask) {
  int bid = blockIdx.x;
  int swz = (bid & 7)*72 + (bid >> 3);      // bijective: 576 = 8*72
  int b = swz / 36, p = swz - b*36;
  int ti = 0;
  while ((ti+1)*(ti+2)/2 <= p) ++ti;
  int tj = p - ti*(ti+1)/2;                 // tj <= ti
  __shared__ _Float16 Ah[8192], Bh2[8192];  // 32 KiB
  int tid = threadIdx.x, wid = tid>>6, lane = tid&63;
  int wm = (wid>>1)*64, wn = (wid&1)*64;
  bool diag = (ti == tj);
  const _Float16* Bh = diag ? Ah : Bh2;
  size_t Abase = ((size_t)(b*8+ti))*65536;
  size_t Bbase = ((size_t)(b*8+tj))*65536;
  f32x4 acc[4][4] = {};
  for (int k0c = 0; k0c < 8; ++k0c) {
    __syncthreads();
    size_t ga = Abase + (size_t)k0c*8192 + wid*2048 + lane*8;
    size_t gb = Bbase + (size_t)k0c*8192 + wid*2048 + lane*8;
    int lb = wid*2048;
    #pragma unroll
    for (int i = 0; i < 4; ++i) GLOAD_LDS16(yf + ga + i*512, &Ah[lb + i*512]);
    if (!diag) {
      #pragma unroll
      for (int i = 0; i < 4; ++i) GLOAD_LDS16(yf + gb + i*512, &Bh2[lb + i*512]);
    }
    __syncthreads();
    #pragma unroll
    for (int kb = 0; kb < 2; ++kb) {
      f16x8 ah[4], bh[4];
      #pragma unroll
      for (int q = 0; q < 4; ++q) {
        ah[q] = *(const f16x8*)&Ah[((kb*8 + (wm>>4) + q)*64 + lane)*8];
        bh[q] = *(const f16x8*)&Bh[((kb*8 + (wn>>4) + q)*64 + lane)*8];
      }
      #pragma unroll
      for (int mi = 0; mi < 4; ++mi)
        #pragma unroll
        for (int ni = 0; ni < 4; ++ni)
          acc[mi][ni] = __builtin_amdgcn_mfma_f32_16x16x32_f16(ah[mi], bh[ni], acc[mi][ni], 0,0,0);
    }
  }
  int rbase = (lane>>4)*4, colL = lane&15;
  #pragma unroll
  for (int mi = 0; mi < 4; ++mi) {
    #pragma unroll
    for (int r2 = 0; r2 < 4; ++r2) {
      int t_g = ti*128 + wm + mi*16 + rbase + r2;
      int git = b*NS + t_g;
      uint8_t* Mrow = Mmask + (size_t)git*NS;
      #pragma unroll
      for (int ni = 0; ni < 4; ++ni) {
        int s_g = tj*128 + wn + ni*16 + colL;
        if (s_g > t_g) continue;
        float sim = acc[mi][ni][r2];
        uint8_t v = (s_g == t_g) ? 1 : ((sim > 0.9f) ? 1 : 0);
        if (s_g < t_g && fabsf(sim - 0.9f) <= SIM_BAND) v = 2;   // borderline: softmax decides exactly
        Mrow[s_g] = v;
      }
    }
  }
}

// ---------------- K4 (fused): blocks 0..511 = gemm_ht; 512..4607 = softmax(+inline recheck) ----------------
#define HT_STAGE(AW, BW, ks) do { \
    size_t ga_ = Abase + (size_t)(ks)*4096 + wid*1024 + lane*8; \
    size_t gb_ = Bbase + (size_t)(ks)*4096 + wid*1024 + lane*8; \
    int lb_ = wid*1024; \
    GLOAD_LDS16(Wf + ga_,       &AW[lb_]); \
    GLOAD_LDS16(Wf + ga_ + 512, &AW[lb_ + 512]); \
    GLOAD_LDS16(yf + gb_,       &BW[lb_]); \
    GLOAD_LDS16(yf + gb_ + 512, &BW[lb_ + 512]); \
  } while(0)

#define F16_COMPUTE(AW, BW) do { \
    f16x8 a_[4], b_[4]; \
    _Pragma("unroll") \
    for (int q_ = 0; q_ < 4; ++q_) { \
      a_[q_] = *(const f16x8*)&(AW)[(((wm>>4) + q_)*64 + lane)*8]; \
      b_[q_] = *(const f16x8*)&(BW)[(((wn>>4) + q_)*64 + lane)*8]; \
    } \
    _Pragma("unroll") \
    for (int mi_ = 0; mi_ < 4; ++mi_) \
      _Pragma("unroll") \
      for (int ni_ = 0; ni_ < 4; ++ni_) \
        acc[mi_][ni_] = __builtin_amdgcn_mfma_f32_16x16x32_f16(a_[mi_], b_[ni_], acc[mi_][ni_], 0,0,0); \
  } while(0)

__global__ __launch_bounds__(256) void k_ht_softmax(const _Float16* __restrict__ Wf,
                                                    const _Float16* __restrict__ yf,
                                                    const float* __restrict__ x,
                                                    const float* __restrict__ rnorm,
                                                    const uint8_t* __restrict__ Mmask,
                                                    const float* __restrict__ a_src,
                                                    const float* __restrict__ a_dst,
                                                    _Float16* __restrict__ htf,
                                                    _Float16* __restrict__ Pf) {
  int bid0 = blockIdx.x;
  if (bid0 < 512) {
    // ---- gemm_ht path (r12-proven) ----
    int swz = (bid0&7)*64 + (bid0>>3);        // bijective: 512 = 8*64
    int mt = swz&3, it = swz>>2;
    int b = it>>3, tblk = it&7;
    __shared__ _Float16 Aw0[4096], Bw0[4096], Aw1[4096], Bw1[4096]; // 16 KiB
    int tid = threadIdx.x, wid = tid>>6, lane = tid&63;
    int wm = (wid>>1)*64, wn = (wid&1)*64;
    size_t Abase = ((size_t)mt)*65536;
    size_t Bbase = ((size_t)(b*8+tblk))*65536;
    f32x4 acc[4][4] = {};
    HT_STAGE(Aw0, Bw0, 0);
    __syncthreads();
    for (int kp = 0; kp < 8; ++kp) {
      HT_STAGE(Aw1, Bw1, kp*2+1);
      F16_COMPUTE(Aw0, Bw0);
      __syncthreads();
      if (kp < 7) HT_STAGE(Aw0, Bw0, kp*2+2);
      F16_COMPUTE(Aw1, Bw1);
      __syncthreads();
    }
    int rbase = (lane>>4)*4, colL = lane&15;
    int n0 = it*128;
    #pragma unroll
    for (int ni = 0; ni < 4; ++ni) {
      int gn = n0 + wn + ni*16 + colL;
      float xn = 1.0f / rnorm[gn];
      int icol = gn & 1023;
      int k0c = icol>>6, cc = icol&63, kb = cc>>5, g = (cc>>3)&3, j = icol&7;
      size_t colbase = ((size_t)((mt*NB + b)*16 + k0c))*8192 + (size_t)(kb*512 + g*16)*8 + j;
      #pragma unroll
      for (int mi = 0; mi < 4; ++mi)
        #pragma unroll
        for (int r2 = 0; r2 < 4; ++r2) {
          int o_local = wm + mi*16 + rbase + r2;
          int m = o_local>>4, r = o_local&15;
          htf[colbase + (size_t)(m*64 + r)*8] = (_Float16)(acc[mi][ni][r2] * xn);
        }
    }
  } else {
    // ---- softmax path with inline exact recheck (mask byte == 2) ----
    int wid = threadIdx.x>>6, lane = threadIdx.x&63;
    int rowid = (bid0 - 512)*4 + wid;         // 4096 blocks x 4 rows
    int t = rowid & (NS-1), b = rowid >> 10;
    int n = t + 1;
    const float* as = a_src + b*NS;
    float adv = a_dst[rowid];
    float rnt = rnorm[rowid];
    const uint8_t* Mrow = Mmask + (size_t)rowid*NS;
    int s0 = lane*16;
    uint4 mb = *(const uint4*)(Mrow + s0);
    unsigned mw[4] = {mb.x, mb.y, mb.z, mb.w};
    float4 a0 = *(const float4*)&as[s0];
    float4 a1 = *(const float4*)&as[s0+4];
    float4 a2 = *(const float4*)&as[s0+8];
    float4 a3 = *(const float4*)&as[s0+12];
    float va[16] = {a0.x,a0.y,a0.z,a0.w, a1.x,a1.y,a1.z,a1.w,
                    a2.x,a2.y,a2.z,a2.w, a3.x,a3.y,a3.z,a3.w};
    float pr[16];
    float lm = -INFINITY;
    #pragma unroll
    for (int k = 0; k < 16; ++k) {
      int s = s0 + k;
      unsigned mbv = (mw[k>>2] >> ((k&3)*8)) & 255u;
      bool on = (s < n) && (mbv != 0u);
      if (on && mbv == 2u) {
        // exact f32 recheck (rare: ~2K pairs globally)
        const float* xt = x + ((size_t)rowid)*ND;
        const float* xs = x + ((size_t)(b*NS + s))*ND;
        float4 d4 = {0.f,0.f,0.f,0.f};
        for (int kk = 0; kk < ND; kk += 4) {
          float4 av = *(const float4*)&xt[kk];
          float4 bv = *(const float4*)&xs[kk];
          d4.x = fmaf(av.x,bv.x,d4.x); d4.y = fmaf(av.y,bv.y,d4.y);
          d4.z = fmaf(av.z,bv.z,d4.z); d4.w = fmaf(av.w,bv.w,d4.w);
        }
        float dot = (d4.x+d4.y)+(d4.z+d4.w);
        on = (dot * rnt * rnorm[b*NS+s]) > 0.9f;
      }
      float vv = adv + va[k];
      float v = (vv > 0.f) ? vv : 0.2f*vv;
      pr[k] = on ? v : -INFINITY;
      lm = fmaxf(lm, pr[k]);
    }
    #pragma unroll
    for (int off = 32; off > 0; off >>= 1) lm = fmaxf(lm, __shfl_xor(lm, off, 64));
    float ls = 0.f;
    #pragma unroll
    for (int k = 0; k < 16; ++k) { pr[k] = __expf(pr[k] - lm); ls += pr[k]; }
    #pragma unroll
    for (int off = 32; off > 0; off >>= 1) ls += __shfl_xor(ls, off, 64);
    float inv = 1.0f / ls;
    int end = ((t >> 7) + 1) << 7;
    if (s0 < end) {
      int m = (t>>4)&7, r = t&15;
      size_t tbase = ((size_t)(b*8 + (t>>7)))*131072;   // pane = 16 tiles x 8192
      #pragma unroll
      for (int h = 0; h < 2; ++h) {
        int icol = s0 + h*8;
        int k0c = icol>>6, cc = icol&63, kb = cc>>5, g = (cc>>3)&3;
        size_t off = tbase + (size_t)k0c*8192 + (size_t)(kb*512 + m*64 + g*16 + r)*8;
        union { _Float16 hh[8]; uint4 u; } pk;
        #pragma unroll
        for (int j = 0; j < 8; ++j) pk.hh[j] = (_Float16)(pr[h*8+j]*inv);
        *(uint4*)&Pf[off] = pk.u;
      }
    }
  }
}

// ---------------- K5: out = relu(P @ h + bias), f16 frag-order, static-dbuf staging ----------------
#define PV_STAGE(AT, BT, ks) do { \
    size_t ga_ = Abase + (size_t)(ks)*4096 + wid*1024 + lane*8; \
    size_t gb_ = Bbase + (size_t)(ks)*4096 + wid*1024 + lane*8; \
    int lb_ = wid*1024; \
    GLOAD_LDS16(Pf  + ga_,       &AT[lb_]); \
    GLOAD_LDS16(Pf  + ga_ + 512, &AT[lb_ + 512]); \
    GLOAD_LDS16(htf + gb_,       &BT[lb_]); \
    GLOAD_LDS16(htf + gb_ + 512, &BT[lb_ + 512]); \
  } while(0)

__global__ __launch_bounds__(256) void k_pv(const _Float16* __restrict__ Pf,
                                            const _Float16* __restrict__ htf,
                                            const float* __restrict__ bias,
                                            float* __restrict__ out) {
  int bid = blockIdx.x;
  int swz = (bid&7)*64 + (bid>>3);          // bijective: 512 = 8*64
  int b = swz>>5, rem = swz&31, mt = rem>>2, nt = rem&3;
  __shared__ _Float16 At0[4096], Bt0[4096], At1[4096], Bt1[4096];  // 16 KiB
  int tid = threadIdx.x, wid = tid>>6, lane = tid&63;
  int wm = (wid>>1)*64, wn = (wid&1)*64;
  size_t Abase = ((size_t)((b*8 + mt)*16))*8192;
  size_t Bbase = ((size_t)((nt*NB + b)*16))*8192;
  f32x4 acc[4][4] = {};
  int nks = 4*(mt+1);                       // even; causal extent
  PV_STAGE(At0, Bt0, 0);
  __syncthreads();
  for (int kp = 0; kp < nks/2; ++kp) {
    PV_STAGE(At1, Bt1, kp*2+1);
    F16_COMPUTE(At0, Bt0);
    __syncthreads();
    if (kp < nks/2 - 1) PV_STAGE(At0, Bt0, kp*2+2);
    F16_COMPUTE(At1, Bt1);
    __syncthreads();
  }
  int m0 = mt*128, n0 = nt*128;
  int rbase = (lane>>4)*4, col = lane&15;
  #pragma unroll
  for (int mi = 0; mi < 4; ++mi)
    #pragma unroll
    for (int ni = 0; ni < 4; ++ni) {
      int gm = m0 + wm + mi*16 + rbase;
      int gn = n0 + wn + ni*16 + col;
      float bv = bias[gn];
      #pragma unroll
      for (int r2 = 0; r2 < 4; ++r2)
        out[((size_t)b*NS + gm + r2)*NO + gn] = fmaxf(acc[mi][ni][r2] + bv, 0.0f);
    }
}

extern "C" void kernel_launch(void* const* d_in, const int* in_sizes, int n_in,
                              void* d_out, int out_size, void* d_ws, size_t ws_size,
                              hipStream_t stream) {
  (void)in_sizes; (void)n_in; (void)out_size; (void)ws_size;
  const float* x       = (const float*)d_in[0];
  const float* W       = (const float*)d_in[1];
  const float* att_src = (const float*)d_in[2];
  const float* att_dst = (const float*)d_in[3];
  const float* bias    = (const float*)d_in[4];
  float* out = (float*)d_out;

  char* ws = (char*)d_ws;
  // ws_size = 256 MiB (measured: harness poison fill WRITE_SIZE = 268,435,456 B).
  // Clean non-aliased layout (~85 MB):
  _Float16* yf    = (_Float16*)(ws + 0);           // 16 MB [prep_y..ht]
  uint8_t*  Mmask = (uint8_t*) (ws + 16777216);    // 16 MB [sim..softmax]
  _Float16* htf   = (_Float16*)(ws + 33554432);    // 16 MB [ht..pv]
  _Float16* Pf    = (_Float16*)(ws + 50331648);    // 32 MB [softmax..pv]
  _Float16* Wf    = (_Float16*)(ws + 83886080);    // 512 KB [prep_w2..ht]
  float*    watt_s= (float*)   (ws + 84410368);    //  2 KB
  float*    watt_d= (float*)   (ws + 84412416);    //  2 KB
  float*    rnorm = (float*)   (ws + 84414464);    // 64 KB
  float*    a_src = (float*)   (ws + 84480000);    // 64 KB
  float*    a_dst = (float*)   (ws + 84545536);    // 64 KB (end ~84.6 MB)

  k_prep_w2  <<<dim3(34),   dim3(256), 0, stream>>>(W, att_src, att_dst, Wf, watt_s, watt_d);
  k_prep_y   <<<dim3(256),  dim3(256), 0, stream>>>(x, yf, rnorm, a_src, a_dst, watt_s, watt_d);
  k_sim_mfma <<<dim3(576),  dim3(256), 0, stream>>>(yf, Mmask);
  k_ht_softmax<<<dim3(4608),dim3(256), 0, stream>>>(Wf, yf, x, rnorm, Mmask, a_src, a_dst, htf, Pf);
  k_pv       <<<dim3(512),  dim3(256), 0, stream>>>(Pf, htf, bias, out);
}

// Round 14
// 132.750 us; speedup vs baseline: 1.1314x; 1.1314x over previous
//
#include <hip/hip_runtime.h>
#include <hip/hip_bf16.h>
#include <stdint.h>

#define NB 16
#define NS 1024
#define ND 512
#define NO 512
#define NROW (NB*NS)   // 16384
#define SIM_BAND 1.5e-3f
#define LIST_CAP 524288

typedef float f32x4 __attribute__((ext_vector_type(4)));
typedef _Float16 f16x8 __attribute__((ext_vector_type(8)));

#define GLOAD_LDS16(g, l) __builtin_amdgcn_global_load_lds( \
    (const __attribute__((address_space(1))) void*)(g), \
    (__attribute__((address_space(3))) void*)(l), 16, 0, 0)

// ---------------- K1: merged W-prep: blocks 0..31 = Wf frag tiles (f16), 32..33 = watt ----------------
__global__ __launch_bounds__(256) void k_prep_w2(const float* __restrict__ W,
                                                 const float* __restrict__ att_src,
                                                 const float* __restrict__ att_dst,
                                                 _Float16* __restrict__ Wf,
                                                 float* __restrict__ watt_s,
                                                 float* __restrict__ watt_d) {
  __shared__ float as_[512], ad_[512];
  int blk = blockIdx.x, tid = threadIdx.x;
  if (blk < 32) {
    int mt = blk>>3, k0c = blk&7;
    size_t base = ((size_t)(mt*8 + k0c))*8192;
    #pragma unroll
    for (int pp = 0; pp < 4; ++pp) {
      int id = pp*256 + tid;
      int kb = id>>9, m = (id>>6)&7, g = (id>>4)&3, r = id&15;
      int o = mt*128 + m*16 + r;
      int d0 = k0c*64 + kb*32 + g*8;
      union { _Float16 h[8]; uint4 u; } pk;
      #pragma unroll
      for (int j = 0; j < 8; ++j) pk.h[j] = (_Float16)W[(size_t)(d0+j)*NO + o];
      *(uint4*)&Wf[base + id*8] = pk.u;
    }
  } else {
    as_[tid] = att_src[tid]; as_[tid+256] = att_src[tid+256];
    ad_[tid] = att_dst[tid]; ad_[tid+256] = att_dst[tid+256];
    __syncthreads();
    int d = (blk-32)*256 + tid;
    const float* wr = W + (size_t)d*NO;
    float s = 0.f, dd = 0.f;
    for (int o = 0; o < NO; o += 4) {
      float4 w = *(const float4*)&wr[o];
      s  = fmaf(w.x, as_[o], fmaf(w.y, as_[o+1], fmaf(w.z, as_[o+2], fmaf(w.w, as_[o+3], s))));
      dd = fmaf(w.x, ad_[o], fmaf(w.y, ad_[o+1], fmaf(w.z, ad_[o+2], fmaf(w.w, ad_[o+3], dd))));
    }
    watt_s[d] = s;
    watt_d[d] = dd;
  }
}

// ---------------- K2: rnorm + a_src/a_dst (via watt) + yf = f16(x*rn) fragment-order ----------------
__global__ __launch_bounds__(256) void k_prep_y(const float* __restrict__ x,
                                                _Float16* __restrict__ yf,
                                                float* __restrict__ rnorm,
                                                float* __restrict__ a_src,
                                                float* __restrict__ a_dst,
                                                const float* __restrict__ watt_s,
                                                const float* __restrict__ watt_d,
                                                int* __restrict__ counter) {
  __shared__ float ws_[512], wd_[512];
  int tid = threadIdx.x, blk = blockIdx.x;
  if (blk == 0 && tid == 0) *counter = 0;
  ws_[tid] = watt_s[tid]; ws_[tid+256] = watt_s[tid+256];
  wd_[tid] = watt_d[tid]; wd_[tid+256] = watt_d[tid+256];
  __syncthreads();
  int r = tid>>2, q = tid&3;
  int grow = blk*64 + r;
  const float* xr = x + (size_t)grow*ND + q*128;
  float ssq = 0.f, as = 0.f, ad = 0.f;
  #pragma unroll
  for (int c8 = 0; c8 < 16; ++c8) {
    float4 v0 = *(const float4*)&xr[c8*8];
    float4 v1 = *(const float4*)&xr[c8*8+4];
    float vv[8] = {v0.x,v0.y,v0.z,v0.w,v1.x,v1.y,v1.z,v1.w};
    #pragma unroll
    for (int j = 0; j < 8; ++j) {
      int c = q*128 + c8*8 + j;
      ssq = fmaf(vv[j], vv[j], ssq);
      as  = fmaf(vv[j], ws_[c], as);
      ad  = fmaf(vv[j], wd_[c], ad);
    }
  }
  ssq += __shfl_xor(ssq, 1, 64); ssq += __shfl_xor(ssq, 2, 64);
  as  += __shfl_xor(as, 1, 64);  as  += __shfl_xor(as, 2, 64);
  ad  += __shfl_xor(ad, 1, 64);  ad  += __shfl_xor(ad, 2, 64);
  float rn = 1.0f / fmaxf(sqrtf(ssq), 1e-12f);
  if (q == 0) { rnorm[grow] = rn; a_src[grow] = as; a_dst[grow] = ad; }
  int trow = grow & (NS-1), b = grow >> 10;
  int m = (trow>>4)&7, rr = trow&15;
  size_t tilebase = ((size_t)(b*8 + (trow>>7)))*65536;
  #pragma unroll
  for (int c8 = 0; c8 < 16; ++c8) {
    int col = q*128 + c8*8;
    int k0c = col>>6, cc = col&63, kb = cc>>5, g = (cc>>3)&3;
    int id = kb*512 + m*64 + g*16 + rr;
    size_t off = tilebase + (size_t)k0c*8192 + id*8;
    float4 v0 = *(const float4*)&xr[c8*8];
    float4 v1 = *(const float4*)&xr[c8*8+4];
    float vv[8] = {v0.x,v0.y,v0.z,v0.w,v1.x,v1.y,v1.z,v1.w};
    union { _Float16 h[8]; uint4 u; } pk;
    #pragma unroll
    for (int j = 0; j < 8; ++j) pk.h[j] = (_Float16)(vv[j]*rn);   // RTN f16, rel err <= 2^-12
    *(uint4*)&yf[off] = pk.u;
  }
}

// ---------------- K3: sim = yf . yf' (f16 MFMA hi-only) -> byte mask + borderline list ----------------
__global__ __launch_bounds__(256) void k_sim_mfma(const _Float16* __restrict__ yf,
                                                  uint8_t* __restrict__ Mmask,
                                                  unsigned int* __restrict__ list,
                                                  int* __restrict__ counter) {
  int bid = blockIdx.x;
  int swz = (bid & 7)*72 + (bid >> 3);      // bijective: 576 = 8*72
  int b = swz / 36, p = swz - b*36;
  int ti = 0;
  while ((ti+1)*(ti+2)/2 <= p) ++ti;
  int tj = p - ti*(ti+1)/2;                 // tj <= ti
  __shared__ _Float16 Ah[8192], Bh2[8192];  // 32 KiB
  int tid = threadIdx.x, wid = tid>>6, lane = tid&63;
  int wm = (wid>>1)*64, wn = (wid&1)*64;
  bool diag = (ti == tj);
  const _Float16* Bh = diag ? Ah : Bh2;
  size_t Abase = ((size_t)(b*8+ti))*65536;
  size_t Bbase = ((size_t)(b*8+tj))*65536;
  f32x4 acc[4][4] = {};
  for (int k0c = 0; k0c < 8; ++k0c) {
    __syncthreads();
    size_t ga = Abase + (size_t)k0c*8192 + wid*2048 + lane*8;
    size_t gb = Bbase + (size_t)k0c*8192 + wid*2048 + lane*8;
    int lb = wid*2048;
    #pragma unroll
    for (int i = 0; i < 4; ++i) GLOAD_LDS16(yf + ga + i*512, &Ah[lb + i*512]);
    if (!diag) {
      #pragma unroll
      for (int i = 0; i < 4; ++i) GLOAD_LDS16(yf + gb + i*512, &Bh2[lb + i*512]);
    }
    __syncthreads();
    #pragma unroll
    for (int kb = 0; kb < 2; ++kb) {
      f16x8 ah[4], bh[4];
      #pragma unroll
      for (int q = 0; q < 4; ++q) {
        ah[q] = *(const f16x8*)&Ah[((kb*8 + (wm>>4) + q)*64 + lane)*8];
        bh[q] = *(const f16x8*)&Bh[((kb*8 + (wn>>4) + q)*64 + lane)*8];
      }
      #pragma unroll
      for (int mi = 0; mi < 4; ++mi)
        #pragma unroll
        for (int ni = 0; ni < 4; ++ni)
          acc[mi][ni] = __builtin_amdgcn_mfma_f32_16x16x32_f16(ah[mi], bh[ni], acc[mi][ni], 0,0,0);
    }
  }
  int rbase = (lane>>4)*4, colL = lane&15;
  #pragma unroll
  for (int mi = 0; mi < 4; ++mi) {
    #pragma unroll
    for (int r2 = 0; r2 < 4; ++r2) {
      int t_g = ti*128 + wm + mi*16 + rbase + r2;
      int git = b*NS + t_g;
      uint8_t* Mrow = Mmask + (size_t)git*NS;
      #pragma unroll
      for (int ni = 0; ni < 4; ++ni) {
        int s_g = tj*128 + wn + ni*16 + colL;
        if (s_g > t_g) continue;
        float sim = acc[mi][ni][r2];
        bool edge = (s_g == t_g) || (sim > 0.9f);
        if (s_g < t_g && fabsf(sim - 0.9f) <= SIM_BAND) {
          int idx = atomicAdd(counter, 1);
          if (idx < LIST_CAP) list[idx] = ((unsigned)b<<20) | ((unsigned)t_g<<10) | (unsigned)s_g;
        }
        Mrow[s_g] = edge ? 1 : 0;
      }
    }
  }
}

// ---------------- K4: exact f32 recheck of borderline pairs -> fix mask bytes ----------------
__global__ __launch_bounds__(256) void k_recheck(const float* __restrict__ x,
                                                 const float* __restrict__ rnorm,
                                                 uint8_t* __restrict__ Mmask,
                                                 const unsigned int* __restrict__ list,
                                                 const int* __restrict__ counter) {
  int n = *counter;
  if (n > LIST_CAP) n = LIST_CAP;
  int gid = blockIdx.x*256 + threadIdx.x;
  for (int i = gid; i < n; i += 256*256) {
    unsigned v = list[i];
    int b = v>>20, t = (v>>10)&1023, s = v&1023;
    const float* xt = x + ((size_t)(b*NS + t))*ND;
    const float* xs = x + ((size_t)(b*NS + s))*ND;
    float4 a4 = {0.f,0.f,0.f,0.f};
    for (int k = 0; k < ND; k += 4) {
      float4 av = *(const float4*)&xt[k];
      float4 bv = *(const float4*)&xs[k];
      a4.x = fmaf(av.x,bv.x,a4.x); a4.y = fmaf(av.y,bv.y,a4.y);
      a4.z = fmaf(av.z,bv.z,a4.z); a4.w = fmaf(av.w,bv.w,a4.w);
    }
    float dot = (a4.x+a4.y)+(a4.z+a4.w);
    float sim = dot * rnorm[b*NS+t] * rnorm[b*NS+s];
    Mmask[((size_t)(b*NS+t))*NS + s] = (sim > 0.9f) ? 1 : 0;
  }
}

// ---------------- K5: htf = (W^T @ yf) * ||x|| (f16), dbuf staging + LDS-staged coalesced output ----
// Single 32KB LDS arena: A buffers at 0 / 8192, B buffers at 4096 / 12288 (f16 elems).
#define HT2_STAGE(OFF, ks) do { \
    size_t ga_ = Abase + (size_t)(ks)*4096 + wid*1024 + lane*8; \
    size_t gb_ = Bbase + (size_t)(ks)*4096 + wid*1024 + lane*8; \
    int lb_ = wid*1024; \
    GLOAD_LDS16(Wf + ga_,       &sbuf[(OFF) + lb_]); \
    GLOAD_LDS16(Wf + ga_ + 512, &sbuf[(OFF) + lb_ + 512]); \
    GLOAD_LDS16(yf + gb_,       &sbuf[(OFF) + 4096 + lb_]); \
    GLOAD_LDS16(yf + gb_ + 512, &sbuf[(OFF) + 4096 + lb_ + 512]); \
  } while(0)

#define HT2_COMPUTE(OFF) do { \
    f16x8 a_[4], b_[4]; \
    _Pragma("unroll") \
    for (int q_ = 0; q_ < 4; ++q_) { \
      a_[q_] = *(const f16x8*)&sbuf[(OFF) + (((wm>>4) + q_)*64 + lane)*8]; \
      b_[q_] = *(const f16x8*)&sbuf[(OFF) + 4096 + (((wn>>4) + q_)*64 + lane)*8]; \
    } \
    _Pragma("unroll") \
    for (int mi_ = 0; mi_ < 4; ++mi_) \
      _Pragma("unroll") \
      for (int ni_ = 0; ni_ < 4; ++ni_) \
        acc[mi_][ni_] = __builtin_amdgcn_mfma_f32_16x16x32_f16(a_[mi_], b_[ni_], acc[mi_][ni_], 0,0,0); \
  } while(0)

__global__ __launch_bounds__(256) void k_gemm_ht(const _Float16* __restrict__ Wf,
                                                 const _Float16* __restrict__ yf,
                                                 const float* __restrict__ rnorm,
                                                 _Float16* __restrict__ htf) {
  int bid = blockIdx.x;
  int swz = (bid&7)*64 + (bid>>3);          // bijective: 512 = 8*64
  int mt = swz&3, it = swz>>2;
  int b = it>>3, tblk = it&7;
  __shared__ __align__(16) _Float16 sbuf[16384];   // 32 KiB arena (staging, then output)
  int tid = threadIdx.x, wid = tid>>6, lane = tid&63;
  int wm = (wid>>1)*64, wn = (wid&1)*64;
  size_t Abase = ((size_t)mt)*65536;
  size_t Bbase = ((size_t)(b*8+tblk))*65536;
  f32x4 acc[4][4] = {};
  HT2_STAGE(0, 0);
  __syncthreads();
  for (int kp = 0; kp < 8; ++kp) {
    HT2_STAGE(8192, kp*2+1);
    HT2_COMPUTE(0);
    __syncthreads();
    if (kp < 7) HT2_STAGE(0, kp*2+2);
    HT2_COMPUTE(8192);
    __syncthreads();
  }
  // stage f16 output in frag order in LDS, then linear coalesced store (block span = 32KB contiguous)
  {
    int rbase = (lane>>4)*4, colL = lane&15;
    #pragma unroll
    for (int ni = 0; ni < 4; ++ni) {
      int i_local = wn + ni*16 + colL;
      int gn = it*128 + i_local;
      float xn = 1.0f / rnorm[gn];
      int tsel = i_local>>6, ic = i_local&63;
      int kb = ic>>5, g = (ic>>3)&3, j = ic&7;
      int base = tsel*8192 + (kb*512 + g*16)*8 + j;
      #pragma unroll
      for (int mi = 0; mi < 4; ++mi)
        #pragma unroll
        for (int r2 = 0; r2 < 4; ++r2) {
          int o_local = wm + mi*16 + rbase + r2;
          int m = o_local>>4, r = o_local&15;
          sbuf[base + (m*64 + r)*8] = (_Float16)(acc[mi][ni][r2] * xn);
        }
    }
  }
  __syncthreads();
  {
    size_t gbase = ((size_t)((mt*NB + b)*16 + tblk*2))*8192;
    const uint4* src = (const uint4*)sbuf;
    uint4* dst = (uint4*)(htf + gbase);
    #pragma unroll
    for (int k = 0; k < 8; ++k) dst[tid + k*256] = src[tid + k*256];
  }
}

// ---------------- K6: masked softmax -> Pf (f16 frag-order), LDS-staged 64B-coalesced writes ----------
__global__ __launch_bounds__(256) void k_softmax(const uint8_t* __restrict__ Mmask,
                                                 const float* __restrict__ a_src,
                                                 const float* __restrict__ a_dst,
                                                 _Float16* __restrict__ Pf) {
  __shared__ __align__(16) _Float16 pbuf[4][1032];   // +8 pad: rows land on distinct banks
  int wid = threadIdx.x>>6, lane = threadIdx.x&63;
  int rowid = blockIdx.x*4 + wid;           // grid 4096; block rows share pane & m
  int t = rowid & (NS-1), b = rowid >> 10;
  int n = t + 1;
  const float* as = a_src + b*NS;
  float adv = a_dst[rowid];
  const uint8_t* Mrow = Mmask + (size_t)rowid*NS;
  int s0 = lane*16;
  uint4 mb = *(const uint4*)(Mrow + s0);
  unsigned mw[4] = {mb.x, mb.y, mb.z, mb.w};
  float4 a0 = *(const float4*)&as[s0];
  float4 a1 = *(const float4*)&as[s0+4];
  float4 a2 = *(const float4*)&as[s0+8];
  float4 a3 = *(const float4*)&as[s0+12];
  float va[16] = {a0.x,a0.y,a0.z,a0.w, a1.x,a1.y,a1.z,a1.w,
                  a2.x,a2.y,a2.z,a2.w, a3.x,a3.y,a3.z,a3.w};
  float pr[16];
  float lm = -INFINITY;
  #pragma unroll
  for (int k = 0; k < 16; ++k) {
    int s = s0 + k;
    bool on = (s < n) && (((mw[k>>2] >> ((k&3)*8)) & 255u) != 0u);
    float vv = adv + va[k];
    float v = (vv > 0.f) ? vv : 0.2f*vv;
    pr[k] = on ? v : -INFINITY;
    lm = fmaxf(lm, pr[k]);
  }
  #pragma unroll
  for (int off = 32; off > 0; off >>= 1) lm = fmaxf(lm, __shfl_xor(lm, off, 64));
  float ls = 0.f;
  #pragma unroll
  for (int k = 0; k < 16; ++k) { pr[k] = __expf(pr[k] - lm); ls += pr[k]; }
  #pragma unroll
  for (int off = 32; off > 0; off >>= 1) ls += __shfl_xor(ls, off, 64);
  float inv = 1.0f / ls;
  union { _Float16 hh[8]; uint4 u; } pk0, pk1;
  #pragma unroll
  for (int j = 0; j < 8; ++j) pk0.hh[j] = (_Float16)(pr[j]*inv);
  #pragma unroll
  for (int j = 0; j < 8; ++j) pk1.hh[j] = (_Float16)(pr[8+j]*inv);
  *(uint4*)&pbuf[wid][s0]   = pk0.u;
  *(uint4*)&pbuf[wid][s0+8] = pk1.u;
  __syncthreads();
  // cooperative store: 4 rows (adjacent r) combine into 64B-contiguous chunks
  int t0 = (blockIdx.x*4) & (NS-1);
  int b0 = (blockIdx.x*4) >> 10;
  int end = ((t0 >> 7) + 1) << 7;
  int m = (t0>>4)&7, r0 = t0&15;
  size_t tbase = ((size_t)(b0*8 + (t0>>7)))*131072;   // pane = 16 tiles x 8192
  int nslots = (end>>3)*4;
  for (int u = threadIdx.x; u < nslots; u += 256) {
    int rr = u&3, c8 = u>>2;
    int icol = c8*8;
    int k0c = icol>>6, kb = (icol>>5)&1, g = (icol>>3)&3;
    uint4 v = *(const uint4*)&pbuf[rr][icol];
    *(uint4*)&Pf[tbase + (size_t)k0c*8192 + (size_t)(kb*512 + m*64 + g*16 + r0 + rr)*8] = v;
  }
}

// ---------------- K7: out = relu(P @ h + bias), f16 frag-order, static-dbuf staging ----------------
#define PV_STAGE(AT, BT, ks) do { \
    size_t ga_ = Abase + (size_t)(ks)*4096 + wid*1024 + lane*8; \
    size_t gb_ = Bbase + (size_t)(ks)*4096 + wid*1024 + lane*8; \
    int lb_ = wid*1024; \
    GLOAD_LDS16(Pf  + ga_,       &AT[lb_]); \
    GLOAD_LDS16(Pf  + ga_ + 512, &AT[lb_ + 512]); \
    GLOAD_LDS16(htf + gb_,       &BT[lb_]); \
    GLOAD_LDS16(htf + gb_ + 512, &BT[lb_ + 512]); \
  } while(0)

#define F16_COMPUTE(AW, BW) do { \
    f16x8 a_[4], b_[4]; \
    _Pragma("unroll") \
    for (int q_ = 0; q_ < 4; ++q_) { \
      a_[q_] = *(const f16x8*)&(AW)[(((wm>>4) + q_)*64 + lane)*8]; \
      b_[q_] = *(const f16x8*)&(BW)[(((wn>>4) + q_)*64 + lane)*8]; \
    } \
    _Pragma("unroll") \
    for (int mi_ = 0; mi_ < 4; ++mi_) \
      _Pragma("unroll") \
      for (int ni_ = 0; ni_ < 4; ++ni_) \
        acc[mi_][ni_] = __builtin_amdgcn_mfma_f32_16x16x32_f16(a_[mi_], b_[ni_], acc[mi_][ni_], 0,0,0); \
  } while(0)

__global__ __launch_bounds__(256) void k_pv(const _Float16* __restrict__ Pf,
                                            const _Float16* __restrict__ htf,
                                            const float* __restrict__ bias,
                                            float* __restrict__ out) {
  int bid = blockIdx.x;
  int swz = (bid&7)*64 + (bid>>3);          // bijective: 512 = 8*64
  int b = swz>>5, rem = swz&31, mt = rem>>2, nt = rem&3;
  __shared__ _Float16 At0[4096], Bt0[4096], At1[4096], Bt1[4096];  // 16 KiB
  int tid = threadIdx.x, wid = tid>>6, lane = tid&63;
  int wm = (wid>>1)*64, wn = (wid&1)*64;
  size_t Abase = ((size_t)((b*8 + mt)*16))*8192;
  size_t Bbase = ((size_t)((nt*NB + b)*16))*8192;
  f32x4 acc[4][4] = {};
  int nks = 4*(mt+1);                       // even; causal extent
  PV_STAGE(At0, Bt0, 0);
  __syncthreads();
  for (int kp = 0; kp < nks/2; ++kp) {
    PV_STAGE(At1, Bt1, kp*2+1);
    F16_COMPUTE(At0, Bt0);
    __syncthreads();
    if (kp < nks/2 - 1) PV_STAGE(At0, Bt0, kp*2+2);
    F16_COMPUTE(At1, Bt1);
    __syncthreads();
  }
  int m0 = mt*128, n0 = nt*128;
  int rbase = (lane>>4)*4, col = lane&15;
  #pragma unroll
  for (int mi = 0; mi < 4; ++mi)
    #pragma unroll
    for (int ni = 0; ni < 4; ++ni) {
      int gm = m0 + wm + mi*16 + rbase;
      int gn = n0 + wn + ni*16 + col;
      float bv = bias[gn];
      #pragma unroll
      for (int r2 = 0; r2 < 4; ++r2)
        out[((size_t)b*NS + gm + r2)*NO + gn] = fmaxf(acc[mi][ni][r2] + bv, 0.0f);
    }
}

extern "C" void kernel_launch(void* const* d_in, const int* in_sizes, int n_in,
                              void* d_out, int out_size, void* d_ws, size_t ws_size,
                              hipStream_t stream) {
  (void)in_sizes; (void)n_in; (void)out_size; (void)ws_size;
  const float* x       = (const float*)d_in[0];
  const float* W       = (const float*)d_in[1];
  const float* att_src = (const float*)d_in[2];
  const float* att_dst = (const float*)d_in[3];
  const float* bias    = (const float*)d_in[4];
  float* out = (float*)d_out;

  char* ws = (char*)d_ws;
  // ws_size = 256 MiB; clean non-aliased layout (~87 MB):
  _Float16*     yf    = (_Float16*)    (ws + 0);           // 16 MB [prep_y..ht]
  uint8_t*      Mmask = (uint8_t*)     (ws + 16777216);    // 16 MB [sim..softmax]
  _Float16*     htf   = (_Float16*)    (ws + 33554432);    // 16 MB [ht..pv]
  _Float16*     Pf    = (_Float16*)    (ws + 50331648);    // 32 MB [softmax..pv]
  _Float16*     Wf    = (_Float16*)    (ws + 83886080);    // 512 KB [prep_w2..ht]
  float*        watt_s= (float*)       (ws + 84410368);    //  2 KB
  float*        watt_d= (float*)       (ws + 84412416);    //  2 KB
  float*        rnorm = (float*)       (ws + 84414464);    // 64 KB
  float*        a_src = (float*)       (ws + 84480000);    // 64 KB
  float*        a_dst = (float*)       (ws + 84545536);    // 64 KB
  unsigned int* list  = (unsigned int*)(ws + 84611072);    //  2 MB [sim..recheck]
  int*          cnt   = (int*)         (ws + 86708224);    // 64 B

  k_prep_w2 <<<dim3(34),   dim3(256), 0, stream>>>(W, att_src, att_dst, Wf, watt_s, watt_d);
  k_prep_y  <<<dim3(256),  dim3(256), 0, stream>>>(x, yf, rnorm, a_src, a_dst, watt_s, watt_d, cnt);
  k_sim_mfma<<<dim3(576),  dim3(256), 0, stream>>>(yf, Mmask, list, cnt);
  k_recheck <<<dim3(256),  dim3(256), 0, stream>>>(x, rnorm, Mmask, list, cnt);
  k_gemm_ht <<<dim3(512),  dim3(256), 0, stream>>>(Wf, yf, rnorm, htf);
  k_softmax <<<dim3(4096), dim3(256), 0, stream>>>(Mmask, a_src, a_dst, Pf);
  k_pv      <<<dim3(512),  dim3(256), 0, stream>>>(Pf, htf, bias, out);
}

// Round 15
// 129.845 us; speedup vs baseline: 1.1568x; 1.0224x over previous
//
#include <hip/hip_runtime.h>
#include <hip/hip_bf16.h>
#include <stdint.h>

#define NB 16
#define NS 1024
#define ND 512
#define NO 512
#define NROW (NB*NS)   // 16384
#define SIM_BAND 1.5e-3f
#define LIST_CAP 524288

typedef float f32x4 __attribute__((ext_vector_type(4)));
typedef _Float16 f16x8 __attribute__((ext_vector_type(8)));

#define GLOAD_LDS16(g, l) __builtin_amdgcn_global_load_lds( \
    (const __attribute__((address_space(1))) void*)(g), \
    (__attribute__((address_space(3))) void*)(l), 16, 0, 0)

// ---------------- K1: merged W-prep: blocks 0..31 = Wf frag tiles (f16), 32..33 = watt ----------------
__global__ __launch_bounds__(256) void k_prep_w2(const float* __restrict__ W,
                                                 const float* __restrict__ att_src,
                                                 const float* __restrict__ att_dst,
                                                 _Float16* __restrict__ Wf,
                                                 float* __restrict__ watt_s,
                                                 float* __restrict__ watt_d) {
  __shared__ float as_[512], ad_[512];
  int blk = blockIdx.x, tid = threadIdx.x;
  if (blk < 32) {
    int mt = blk>>3, k0c = blk&7;
    size_t base = ((size_t)(mt*8 + k0c))*8192;
    #pragma unroll
    for (int pp = 0; pp < 4; ++pp) {
      int id = pp*256 + tid;
      int kb = id>>9, m = (id>>6)&7, g = (id>>4)&3, r = id&15;
      int o = mt*128 + m*16 + r;
      int d0 = k0c*64 + kb*32 + g*8;
      union { _Float16 h[8]; uint4 u; } pk;
      #pragma unroll
      for (int j = 0; j < 8; ++j) pk.h[j] = (_Float16)W[(size_t)(d0+j)*NO + o];
      *(uint4*)&Wf[base + id*8] = pk.u;
    }
  } else {
    as_[tid] = att_src[tid]; as_[tid+256] = att_src[tid+256];
    ad_[tid] = att_dst[tid]; ad_[tid+256] = att_dst[tid+256];
    __syncthreads();
    int d = (blk-32)*256 + tid;
    const float* wr = W + (size_t)d*NO;
    float s = 0.f, dd = 0.f;
    for (int o = 0; o < NO; o += 4) {
      float4 w = *(const float4*)&wr[o];
      s  = fmaf(w.x, as_[o], fmaf(w.y, as_[o+1], fmaf(w.z, as_[o+2], fmaf(w.w, as_[o+3], s))));
      dd = fmaf(w.x, ad_[o], fmaf(w.y, ad_[o+1], fmaf(w.z, ad_[o+2], fmaf(w.w, ad_[o+3], dd))));
    }
    watt_s[d] = s;
    watt_d[d] = dd;
  }
}

// ---------------- K2: rnorm + a_src/a_dst (via watt) + yf = f16(x*rn) fragment-order ----------------
__global__ __launch_bounds__(256) void k_prep_y(const float* __restrict__ x,
                                                _Float16* __restrict__ yf,
                                                float* __restrict__ rnorm,
                                                float* __restrict__ a_src,
                                                float* __restrict__ a_dst,
                                                const float* __restrict__ watt_s,
                                                const float* __restrict__ watt_d,
                                                int* __restrict__ counter) {
  __shared__ float ws_[512], wd_[512];
  int tid = threadIdx.x, blk = blockIdx.x;
  if (blk == 0 && tid == 0) *counter = 0;
  ws_[tid] = watt_s[tid]; ws_[tid+256] = watt_s[tid+256];
  wd_[tid] = watt_d[tid]; wd_[tid+256] = watt_d[tid+256];
  __syncthreads();
  int r = tid>>2, q = tid&3;
  int grow = blk*64 + r;
  const float* xr = x + (size_t)grow*ND + q*128;
  float ssq = 0.f, as = 0.f, ad = 0.f;
  #pragma unroll
  for (int c8 = 0; c8 < 16; ++c8) {
    float4 v0 = *(const float4*)&xr[c8*8];
    float4 v1 = *(const float4*)&xr[c8*8+4];
    float vv[8] = {v0.x,v0.y,v0.z,v0.w,v1.x,v1.y,v1.z,v1.w};
    #pragma unroll
    for (int j = 0; j < 8; ++j) {
      int c = q*128 + c8*8 + j;
      ssq = fmaf(vv[j], vv[j], ssq);
      as  = fmaf(vv[j], ws_[c], as);
      ad  = fmaf(vv[j], wd_[c], ad);
    }
  }
  ssq += __shfl_xor(ssq, 1, 64); ssq += __shfl_xor(ssq, 2, 64);
  as  += __shfl_xor(as, 1, 64);  as  += __shfl_xor(as, 2, 64);
  ad  += __shfl_xor(ad, 1, 64);  ad  += __shfl_xor(ad, 2, 64);
  float rn = 1.0f / fmaxf(sqrtf(ssq), 1e-12f);
  if (q == 0) { rnorm[grow] = rn; a_src[grow] = as; a_dst[grow] = ad; }
  int trow = grow & (NS-1), b = grow >> 10;
  int m = (trow>>4)&7, rr = trow&15;
  size_t tilebase = ((size_t)(b*8 + (trow>>7)))*65536;
  #pragma unroll
  for (int c8 = 0; c8 < 16; ++c8) {
    int col = q*128 + c8*8;
    int k0c = col>>6, cc = col&63, kb = cc>>5, g = (cc>>3)&3;
    int id = kb*512 + m*64 + g*16 + rr;
    size_t off = tilebase + (size_t)k0c*8192 + id*8;
    float4 v0 = *(const float4*)&xr[c8*8];
    float4 v1 = *(const float4*)&xr[c8*8+4];
    float vv[8] = {v0.x,v0.y,v0.z,v0.w,v1.x,v1.y,v1.z,v1.w};
    union { _Float16 h[8]; uint4 u; } pk;
    #pragma unroll
    for (int j = 0; j < 8; ++j) pk.h[j] = (_Float16)(vv[j]*rn);   // RTN f16, rel err <= 2^-12
    *(uint4*)&yf[off] = pk.u;
  }
}

// ---------------- K3: sim = yf . yf' (f16 MFMA hi-only) -> BIT mask (ballot) + borderline list ----
__global__ __launch_bounds__(256) void k_sim_mfma(const _Float16* __restrict__ yf,
                                                  uint16_t* __restrict__ Mbits,
                                                  unsigned int* __restrict__ list,
                                                  int* __restrict__ counter) {
  int bid = blockIdx.x;
  int swz = (bid & 7)*72 + (bid >> 3);      // bijective: 576 = 8*72
  int b = swz / 36, p = swz - b*36;
  int ti = 0;
  while ((ti+1)*(ti+2)/2 <= p) ++ti;
  int tj = p - ti*(ti+1)/2;                 // tj <= ti
  __shared__ _Float16 Ah[8192], Bh2[8192];  // 32 KiB
  int tid = threadIdx.x, wid = tid>>6, lane = tid&63;
  int wm = (wid>>1)*64, wn = (wid&1)*64;
  bool diag = (ti == tj);
  const _Float16* Bh = diag ? Ah : Bh2;
  size_t Abase = ((size_t)(b*8+ti))*65536;
  size_t Bbase = ((size_t)(b*8+tj))*65536;
  f32x4 acc[4][4] = {};
  for (int k0c = 0; k0c < 8; ++k0c) {
    __syncthreads();
    size_t ga = Abase + (size_t)k0c*8192 + wid*2048 + lane*8;
    size_t gb = Bbase + (size_t)k0c*8192 + wid*2048 + lane*8;
    int lb = wid*2048;
    #pragma unroll
    for (int i = 0; i < 4; ++i) GLOAD_LDS16(yf + ga + i*512, &Ah[lb + i*512]);
    if (!diag) {
      #pragma unroll
      for (int i = 0; i < 4; ++i) GLOAD_LDS16(yf + gb + i*512, &Bh2[lb + i*512]);
    }
    __syncthreads();
    #pragma unroll
    for (int kb = 0; kb < 2; ++kb) {
      f16x8 ah[4], bh[4];
      #pragma unroll
      for (int q = 0; q < 4; ++q) {
        ah[q] = *(const f16x8*)&Ah[((kb*8 + (wm>>4) + q)*64 + lane)*8];
        bh[q] = *(const f16x8*)&Bh[((kb*8 + (wn>>4) + q)*64 + lane)*8];
      }
      #pragma unroll
      for (int mi = 0; mi < 4; ++mi)
        #pragma unroll
        for (int ni = 0; ni < 4; ++ni)
          acc[mi][ni] = __builtin_amdgcn_mfma_f32_16x16x32_f16(ah[mi], bh[ni], acc[mi][ni], 0,0,0);
    }
  }
  int hi = lane>>4, colL = lane&15;
  #pragma unroll
  for (int mi = 0; mi < 4; ++mi) {
    #pragma unroll
    for (int r2 = 0; r2 < 4; ++r2) {
      int t_g = ti*128 + wm + mi*16 + hi*4 + r2;
      int git = b*NS + t_g;
      #pragma unroll
      for (int ni = 0; ni < 4; ++ni) {
        int s_g = tj*128 + wn + ni*16 + colL;
        float sim = acc[mi][ni][r2];
        bool bit = (s_g == t_g) || (s_g < t_g && sim > 0.9f);
        if (s_g < t_g && fabsf(sim - 0.9f) <= SIM_BAND) {
          int idx = atomicAdd(counter, 1);
          if (idx < LIST_CAP) list[idx] = ((unsigned)b<<20) | ((unsigned)t_g<<10) | (unsigned)s_g;
        }
        unsigned long long bal = __ballot(bit);
        if (colL == 0) {
          uint16_t slice = (uint16_t)((bal >> (hi*16)) & 0xFFFFull);
          Mbits[(size_t)git*64 + ((tj*128 + wn + ni*16)>>4)] = slice;
        }
      }
    }
  }
}

// ---------------- K4 (fused): blocks 0..511 = gemm_ht; 512..767 = bit recheck ----------------
#define HT2_STAGE(OFF, ks) do { \
    size_t ga_ = Abase + (size_t)(ks)*4096 + wid*1024 + lane*8; \
    size_t gb_ = Bbase + (size_t)(ks)*4096 + wid*1024 + lane*8; \
    int lb_ = wid*1024; \
    GLOAD_LDS16(Wf + ga_,       &sbuf[(OFF) + lb_]); \
    GLOAD_LDS16(Wf + ga_ + 512, &sbuf[(OFF) + lb_ + 512]); \
    GLOAD_LDS16(yf + gb_,       &sbuf[(OFF) + 4096 + lb_]); \
    GLOAD_LDS16(yf + gb_ + 512, &sbuf[(OFF) + 4096 + lb_ + 512]); \
  } while(0)

#define HT2_COMPUTE(OFF) do { \
    f16x8 a_[4], b_[4]; \
    _Pragma("unroll") \
    for (int q_ = 0; q_ < 4; ++q_) { \
      a_[q_] = *(const f16x8*)&sbuf[(OFF) + (((wm>>4) + q_)*64 + lane)*8]; \
      b_[q_] = *(const f16x8*)&sbuf[(OFF) + 4096 + (((wn>>4) + q_)*64 + lane)*8]; \
    } \
    _Pragma("unroll") \
    for (int mi_ = 0; mi_ < 4; ++mi_) \
      _Pragma("unroll") \
      for (int ni_ = 0; ni_ < 4; ++ni_) \
        acc[mi_][ni_] = __builtin_amdgcn_mfma_f32_16x16x32_f16(a_[mi_], b_[ni_], acc[mi_][ni_], 0,0,0); \
  } while(0)

__global__ __launch_bounds__(256) void k_ht_recheck(const _Float16* __restrict__ Wf,
                                                    const _Float16* __restrict__ yf,
                                                    const float* __restrict__ x,
                                                    const float* __restrict__ rnorm,
                                                    _Float16* __restrict__ htf,
                                                    uint32_t* __restrict__ Mw,
                                                    const unsigned int* __restrict__ list,
                                                    const int* __restrict__ counter) {
  __shared__ __align__(16) _Float16 sbuf[16384];   // 32 KiB arena
  int bid0 = blockIdx.x;
  if (bid0 < 512) {
    int swz = (bid0&7)*64 + (bid0>>3);        // bijective: 512 = 8*64
    int mt = swz&3, it = swz>>2;
    int b = it>>3, tblk = it&7;
    int tid = threadIdx.x, wid = tid>>6, lane = tid&63;
    int wm = (wid>>1)*64, wn = (wid&1)*64;
    size_t Abase = ((size_t)mt)*65536;
    size_t Bbase = ((size_t)(b*8+tblk))*65536;
    f32x4 acc[4][4] = {};
    HT2_STAGE(0, 0);
    __syncthreads();
    for (int kp = 0; kp < 8; ++kp) {
      HT2_STAGE(8192, kp*2+1);
      HT2_COMPUTE(0);
      __syncthreads();
      if (kp < 7) HT2_STAGE(0, kp*2+2);
      HT2_COMPUTE(8192);
      __syncthreads();
    }
    {
      int rbase = (lane>>4)*4, colL = lane&15;
      #pragma unroll
      for (int ni = 0; ni < 4; ++ni) {
        int i_local = wn + ni*16 + colL;
        int gn = it*128 + i_local;
        float xn = 1.0f / rnorm[gn];
        int tsel = i_local>>6, ic = i_local&63;
        int kb = ic>>5, g = (ic>>3)&3, j = ic&7;
        int base = tsel*8192 + (kb*512 + g*16)*8 + j;
        #pragma unroll
        for (int mi = 0; mi < 4; ++mi)
          #pragma unroll
          for (int r2 = 0; r2 < 4; ++r2) {
            int o_local = wm + mi*16 + rbase + r2;
            int m = o_local>>4, r = o_local&15;
            sbuf[base + (m*64 + r)*8] = (_Float16)(acc[mi][ni][r2] * xn);
          }
      }
    }
    __syncthreads();
    {
      size_t gbase = ((size_t)((mt*NB + b)*16 + tblk*2))*8192;
      const uint4* src = (const uint4*)sbuf;
      uint4* dst = (uint4*)(htf + gbase);
      #pragma unroll
      for (int k = 0; k < 8; ++k) dst[tid + k*256] = src[tid + k*256];
    }
  } else {
    // ---- exact f32 recheck of borderline pairs -> fix mask bits (r5-proven) ----
    int n = *counter;
    if (n > LIST_CAP) n = LIST_CAP;
    int gid = (bid0 - 512)*256 + threadIdx.x;
    for (int i = gid; i < n; i += 256*256) {
      unsigned v = list[i];
      int b = v>>20, t = (v>>10)&1023, s = v&1023;
      const float* xt = x + ((size_t)(b*NS + t))*ND;
      const float* xs = x + ((size_t)(b*NS + s))*ND;
      float4 a4 = {0.f,0.f,0.f,0.f};
      for (int k = 0; k < ND; k += 4) {
        float4 av = *(const float4*)&xt[k];
        float4 bv = *(const float4*)&xs[k];
        a4.x = fmaf(av.x,bv.x,a4.x); a4.y = fmaf(av.y,bv.y,a4.y);
        a4.z = fmaf(av.z,bv.z,a4.z); a4.w = fmaf(av.w,bv.w,a4.w);
      }
      float dot = (a4.x+a4.y)+(a4.z+a4.w);
      float sim = dot * rnorm[b*NS+t] * rnorm[b*NS+s];
      int git = b*NS + t;
      uint32_t bmask = 1u << (s&31);
      if (sim > 0.9f) atomicOr (&Mw[(size_t)git*32 + (s>>5)], bmask);
      else            atomicAnd(&Mw[(size_t)git*32 + (s>>5)], ~bmask);
    }
  }
}

// ---------------- K5: masked softmax (bit mask) -> Pf (f16 frag-order), LDS-staged writes ----------
__global__ __launch_bounds__(256) void k_softmax(const uint32_t* __restrict__ Mw,
                                                 const float* __restrict__ a_src,
                                                 const float* __restrict__ a_dst,
                                                 _Float16* __restrict__ Pf) {
  __shared__ __align__(16) _Float16 pbuf[4][1032];
  int wid = threadIdx.x>>6, lane = threadIdx.x&63;
  int rowid = blockIdx.x*4 + wid;           // grid 4096; block rows share pane & m
  int t = rowid & (NS-1), b = rowid >> 10;
  int n = t + 1;
  const float* as = a_src + b*NS;
  float adv = a_dst[rowid];
  uint32_t w = Mw[(size_t)rowid*32 + (lane>>1)];
  uint32_t bits16 = (lane&1) ? (w>>16) : (w & 0xFFFFu);
  int s0 = lane*16;
  float4 a0 = *(const float4*)&as[s0];
  float4 a1 = *(const float4*)&as[s0+4];
  float4 a2 = *(const float4*)&as[s0+8];
  float4 a3 = *(const float4*)&as[s0+12];
  float va[16] = {a0.x,a0.y,a0.z,a0.w, a1.x,a1.y,a1.z,a1.w,
                  a2.x,a2.y,a2.z,a2.w, a3.x,a3.y,a3.z,a3.w};
  float pr[16];
  float lm = -INFINITY;
  #pragma unroll
  for (int k = 0; k < 16; ++k) {
    int s = s0 + k;
    bool on = (s < n) && ((bits16>>k)&1);
    float vv = adv + va[k];
    float v = (vv > 0.f) ? vv : 0.2f*vv;
    pr[k] = on ? v : -INFINITY;
    lm = fmaxf(lm, pr[k]);
  }
  #pragma unroll
  for (int off = 32; off > 0; off >>= 1) lm = fmaxf(lm, __shfl_xor(lm, off, 64));
  float ls = 0.f;
  #pragma unroll
  for (int k = 0; k < 16; ++k) { pr[k] = __expf(pr[k] - lm); ls += pr[k]; }
  #pragma unroll
  for (int off = 32; off > 0; off >>= 1) ls += __shfl_xor(ls, off, 64);
  float inv = 1.0f / ls;
  union { _Float16 hh[8]; uint4 u; } pk0, pk1;
  #pragma unroll
  for (int j = 0; j < 8; ++j) pk0.hh[j] = (_Float16)(pr[j]*inv);
  #pragma unroll
  for (int j = 0; j < 8; ++j) pk1.hh[j] = (_Float16)(pr[8+j]*inv);
  *(uint4*)&pbuf[wid][s0]   = pk0.u;
  *(uint4*)&pbuf[wid][s0+8] = pk1.u;
  __syncthreads();
  int t0 = (blockIdx.x*4) & (NS-1);
  int b0 = (blockIdx.x*4) >> 10;
  int end = ((t0 >> 7) + 1) << 7;
  int m = (t0>>4)&7, r0 = t0&15;
  size_t tbase = ((size_t)(b0*8 + (t0>>7)))*131072;   // pane = 16 tiles x 8192
  int nslots = (end>>3)*4;
  for (int u = threadIdx.x; u < nslots; u += 256) {
    int rr = u&3, c8 = u>>2;
    int icol = c8*8;
    int k0c = icol>>6, kb = (icol>>5)&1, g = (icol>>3)&3;
    uint4 v = *(const uint4*)&pbuf[rr][icol];
    *(uint4*)&Pf[tbase + (size_t)k0c*8192 + (size_t)(kb*512 + m*64 + g*16 + r0 + rr)*8] = v;
  }
}

// ---------------- K6: out = relu(P @ h + bias), f16 frag-order, static-dbuf staging ----------------
#define PV_STAGE(AT, BT, ks) do { \
    size_t ga_ = Abase + (size_t)(ks)*4096 + wid*1024 + lane*8; \
    size_t gb_ = Bbase + (size_t)(ks)*4096 + wid*1024 + lane*8; \
    int lb_ = wid*1024; \
    GLOAD_LDS16(Pf  + ga_,       &AT[lb_]); \
    GLOAD_LDS16(Pf  + ga_ + 512, &AT[lb_ + 512]); \
    GLOAD_LDS16(htf + gb_,       &BT[lb_]); \
    GLOAD_LDS16(htf + gb_ + 512, &BT[lb_ + 512]); \
  } while(0)

#define F16_COMPUTE(AW, BW) do { \
    f16x8 a_[4], b_[4]; \
    _Pragma("unroll") \
    for (int q_ = 0; q_ < 4; ++q_) { \
      a_[q_] = *(const f16x8*)&(AW)[(((wm>>4) + q_)*64 + lane)*8]; \
      b_[q_] = *(const f16x8*)&(BW)[(((wn>>4) + q_)*64 + lane)*8]; \
    } \
    _Pragma("unroll") \
    for (int mi_ = 0; mi_ < 4; ++mi_) \
      _Pragma("unroll") \
      for (int ni_ = 0; ni_ < 4; ++ni_) \
        acc[mi_][ni_] = __builtin_amdgcn_mfma_f32_16x16x32_f16(a_[mi_], b_[ni_], acc[mi_][ni_], 0,0,0); \
  } while(0)

__global__ __launch_bounds__(256) void k_pv(const _Float16* __restrict__ Pf,
                                            const _Float16* __restrict__ htf,
                                            const float* __restrict__ bias,
                                            float* __restrict__ out) {
  int bid = blockIdx.x;
  int swz = (bid&7)*64 + (bid>>3);          // bijective: 512 = 8*64
  int b = swz>>5, rem = swz&31, mt = rem>>2, nt = rem&3;
  __shared__ _Float16 At0[4096], Bt0[4096], At1[4096], Bt1[4096];  // 16 KiB
  int tid = threadIdx.x, wid = tid>>6, lane = tid&63;
  int wm = (wid>>1)*64, wn = (wid&1)*64;
  size_t Abase = ((size_t)((b*8 + mt)*16))*8192;
  size_t Bbase = ((size_t)((nt*NB + b)*16))*8192;
  f32x4 acc[4][4] = {};
  int nks = 4*(mt+1);                       // even; causal extent
  PV_STAGE(At0, Bt0, 0);
  __syncthreads();
  for (int kp = 0; kp < nks/2; ++kp) {
    PV_STAGE(At1, Bt1, kp*2+1);
    F16_COMPUTE(At0, Bt0);
    __syncthreads();
    if (kp < nks/2 - 1) PV_STAGE(At0, Bt0, kp*2+2);
    F16_COMPUTE(At1, Bt1);
    __syncthreads();
  }
  int m0 = mt*128, n0 = nt*128;
  int rbase = (lane>>4)*4, col = lane&15;
  #pragma unroll
  for (int mi = 0; mi < 4; ++mi)
    #pragma unroll
    for (int ni = 0; ni < 4; ++ni) {
      int gm = m0 + wm + mi*16 + rbase;
      int gn = n0 + wn + ni*16 + col;
      float bv = bias[gn];
      #pragma unroll
      for (int r2 = 0; r2 < 4; ++r2)
        out[((size_t)b*NS + gm + r2)*NO + gn] = fmaxf(acc[mi][ni][r2] + bv, 0.0f);
    }
}

extern "C" void kernel_launch(void* const* d_in, const int* in_sizes, int n_in,
                              void* d_out, int out_size, void* d_ws, size_t ws_size,
                              hipStream_t stream) {
  (void)in_sizes; (void)n_in; (void)out_size; (void)ws_size;
  const float* x       = (const float*)d_in[0];
  const float* W       = (const float*)d_in[1];
  const float* att_src = (const float*)d_in[2];
  const float* att_dst = (const float*)d_in[3];
  const float* bias    = (const float*)d_in[4];
  float* out = (float*)d_out;

  char* ws = (char*)d_ws;
  // ws_size = 256 MiB; clean non-aliased layout (~72 MB):
  _Float16*     yf    = (_Float16*)    (ws + 0);           // 16 MB [prep_y..ht]
  _Float16*     htf   = (_Float16*)    (ws + 16777216);    // 16 MB [ht..pv]
  _Float16*     Pf    = (_Float16*)    (ws + 33554432);    // 32 MB [softmax..pv]
  uint16_t*     Mbits = (uint16_t*)    (ws + 67108864);    //  2 MB [sim..softmax]
  _Float16*     Wf    = (_Float16*)    (ws + 69206016);    // 512 KB [prep_w2..ht]
  float*        watt_s= (float*)       (ws + 69730304);    //  2 KB
  float*        watt_d= (float*)       (ws + 69732352);    //  2 KB
  float*        rnorm = (float*)       (ws + 69734400);    // 64 KB
  float*        a_src = (float*)       (ws + 69799936);    // 64 KB
  float*        a_dst = (float*)       (ws + 69865472);    // 64 KB
  unsigned int* list  = (unsigned int*)(ws + 69931008);    //  2 MB [sim..recheck]
  int*          cnt   = (int*)         (ws + 72028160);    // 64 B

  k_prep_w2   <<<dim3(34),   dim3(256), 0, stream>>>(W, att_src, att_dst, Wf, watt_s, watt_d);
  k_prep_y    <<<dim3(256),  dim3(256), 0, stream>>>(x, yf, rnorm, a_src, a_dst, watt_s, watt_d, cnt);
  k_sim_mfma  <<<dim3(576),  dim3(256), 0, stream>>>(yf, Mbits, list, cnt);
  k_ht_recheck<<<dim3(768),  dim3(256), 0, stream>>>(Wf, yf, x, rnorm, htf, (uint32_t*)Mbits, list, cnt);
  k_softmax   <<<dim3(4096), dim3(256), 0, stream>>>((const uint32_t*)Mbits, a_src, a_dst, Pf);
  k_pv        <<<dim3(512),  dim3(256), 0, stream>>>(Pf, htf, bias, out);
}